// Round 12
// baseline (204.213 us; speedup 1.0000x reference)
//
#include <hip/hip_runtime.h>

#define NN 50000
#define NE 600000
#define DIM 128
#define CAP 40

// workspace layout (~34 MB)
#define OFF_CUR    0         // NN ints (zeroed in k_z); final = exact in-degree
#define OFF_FLAG   401408    // 1 int: is64
#define OFF_SRCL   401920    // NN*CAP ints (slots >= cnt unread: gather masks by cnt)
#define OFF_W1T    8401920   // 32768 B
#define OFF_W2T    8434688   // 32768 B
#define OFF_Y      8467456   // NN*256 B bf16x2 rows, UNSCALED bf16(x)
#define OFF_Z1     21267968  // NN*256 B bf16x2 rows (dinv-prescaled by GEMM-1)

typedef unsigned short u16;
typedef unsigned int u32;
typedef __attribute__((ext_vector_type(8))) short short8;
typedef __attribute__((ext_vector_type(4))) float floatx4;

__device__ __forceinline__ float bflo(u32 u) { return __uint_as_float(u << 16); }
__device__ __forceinline__ float bfhi(u32 u) { return __uint_as_float(u & 0xFFFF0000u); }
__device__ __forceinline__ u16 f2bf(float f) {
    u32 x = __float_as_uint(f);
    return (u16)((x + 0x7FFFu + ((x >> 16) & 1u)) >> 16);  // RNE
}
__device__ __forceinline__ u32 pack2(float hi, float lo) {
    return ((u32)f2bf(hi) << 16) | (u32)f2bf(lo);
}

// ---- k_z: zero cur, transpose both W (f32->bf16), sniff index width --------
__global__ __launch_bounds__(256) void k_z(
    const int* __restrict__ ei, const float* __restrict__ W1,
    const float* __restrict__ W2, char* __restrict__ ws) {
    int* cur = (int*)(ws + OFF_CUR);
    int* flagw = (int*)(ws + OFF_FLAG);
    u16* W1t = (u16*)(ws + OFF_W1T);
    u16* W2t = (u16*)(ws + OFF_W2T);
    int b = blockIdx.x, tid = threadIdx.x;
    for (int i = b * 256 + tid; i < NN; i += 128 * 256) cur[i] = 0;
    const float* W = (b < 64) ? W1 : W2;
    u16* Wt = (b < 64) ? W1t : W2t;
    int e = (b & 63) * 256 + tid;
    int k = e >> 7, n = e & 127;
    Wt[n * DIM + k] = f2bf(W[e]);
    if (b == 0) {
        // int64 indices misread as int32: odd (high) words ~all zero.
        __shared__ int sc;
        if (tid == 0) sc = 0;
        __syncthreads();
        int lc = 0;
        for (int i = tid; i < 1024; i += 256) lc += (ei[2 * i + 1] != 0) ? 1 : 0;
        if (lc) atomicAdd(&sc, lc);
        __syncthreads();
        if (tid == 0) *flagw = (sc < 16) ? 1 : 0;
    }
}

// ---- k_fillpack: 1.6M threads. Every thread packs 8 bf16 of y = bf16(x)
// (unscaled - no degree dependency); first 600k threads also place one edge
// (1 thread/edge: max TLP hides atomic latency; pack traffic hides under it).
// cur counts ALL edges (exact degree); srcs sanitized to [0,NN); overflow
// beyond CAP dropped (P ~ 1e-11).
__global__ __launch_bounds__(256) void k_fillpack(const int* __restrict__ ei,
                                                  const float* __restrict__ x,
                                                  char* __restrict__ ws) {
    int* cur = (int*)(ws + OFF_CUR);
    int* srclist = (int*)(ws + OFF_SRCL);
    int gid = blockIdx.x * 256 + threadIdx.x;  // grid = 6250*256 == NN*32 exactly
    float4 v = ((const float4*)x)[gid];
    uint2 o;
    o.x = pack2(v.y, v.x);
    o.y = pack2(v.w, v.z);
    ((uint2*)(ws + OFF_Y))[gid] = o;
    if (gid < NE) {
        int is64 = *(const int*)(ws + OFF_FLAG);
        int d = is64 ? ei[2 * (NE + gid)] : ei[NE + gid];
        if ((u32)d < NN) {
            int p = atomicAdd(&cur[d], 1);
            if (p < CAP) {
                int s = is64 ? ei[2 * gid] : ei[gid];
                srclist[d * CAP + p] = ((u32)s < NN) ? s : 0;
            }
        }
    }
}

// ---- fused layer: block owns 16 nodes. Gather: quarter-wave (16 lanes x
// dwordx4) per node, 4 nodes/wave in parallel; depth-4 row pipeline + idx
// prefetch; masked tails read self row. dinv recomputed inline from cur
// (rsqrt is ~free vs the ~2.1 TB/s scattered-64B service wall).
// mode 0: input y unscaled -> fma by dinv[s] per row; store bf16 dinv[row]*relu(v)
// mode 1: input z1 prescaled -> plain adds; store f32 relu(v)
__global__ __launch_bounds__(256) void k_layer(
    const u32* __restrict__ y, const char* __restrict__ ws,
    const u16* __restrict__ Bt, const float* __restrict__ bias,
    void* __restrict__ out, int mode) {
    const int* cur = (const int*)(ws + OFF_CUR);
    const int* srclist = (const int*)(ws + OFF_SRCL);
    __shared__ u32 tl[16][68];  // row stride 272B: 16B-aligned for b128 ops
    int tid = threadIdx.x;
    int wv = tid >> 6, lane = tid & 63;
    int grp = lane >> 4, sl16 = lane & 15;
    int node0 = blockIdx.x << 4;
    int nn = wv * 4 + grp;   // tile row 0..15
    int n = node0 + nn;      // this quarter-wave's node
    int craw = cur[n];
    float dn = rsqrtf((float)(craw + 1));  // +1 self-loop; full degree
    int cnt = craw < CAP ? craw : CAP;
    const int* sl = srclist + (size_t)n * CAP;
    int c1 = cnt > 0 ? cnt - 1 : 0;

    // init accumulators from self row
    uint4 us = *(const uint4*)(y + (size_t)n * 64 + sl16 * 4);
    float sw = (mode == 0) ? dn : 1.0f;  // mode 0: self term = dn*y_n (t=dn*acc)
    float a0 = sw * bflo(us.x), a1 = sw * bfhi(us.x);
    float a2 = sw * bflo(us.y), a3 = sw * bfhi(us.y);
    float a4 = sw * bflo(us.z), a5 = sw * bfhi(us.z);
    float a6 = sw * bflo(us.w), a7 = sw * bfhi(us.w);

    // wave-uniform iteration count = max cnt over the 4 groups
    int mx = cnt;
    mx = max(mx, __shfl_xor(mx, 16));
    mx = max(mx, __shfl_xor(mx, 32));

#define SIDX(j) ((j) < cnt ? sl[(j) < c1 ? (j) : c1] : n)  // safe: [0,NN) or self
#define ROW(s) (*(const uint4*)(y + (size_t)(s) * 64 + sl16 * 4))
#define MSK(j) (((j) < cnt) ? 0xFFFFFFFFu : 0u)
    if (mx > 0) {
        int s0 = SIDX(0), s1 = SIDX(1), s2 = SIDX(2), s3 = SIDX(3);
        u32 m0 = MSK(0), m1 = MSK(1), m2 = MSK(2), m3 = MSK(3);
        uint4 u0 = ROW(s0), u1 = ROW(s1), u2 = ROW(s2);
        if (mode == 0) {  // wave-uniform branch
            int c0 = cur[s0], c1v = cur[s1], c2v = cur[s2];
            int sF = s3;
#pragma unroll 2
            for (int i = 0; i < mx; ++i) {
                int sN = SIDX(i + 4);
                uint4 u3 = ROW(sF);
                int c3v = cur[sF];
                float ds = rsqrtf((float)(c0 + 1));
                u32 v;
                v = u0.x & m0; a0 += ds * bflo(v); a1 += ds * bfhi(v);
                v = u0.y & m0; a2 += ds * bflo(v); a3 += ds * bfhi(v);
                v = u0.z & m0; a4 += ds * bflo(v); a5 += ds * bfhi(v);
                v = u0.w & m0; a6 += ds * bflo(v); a7 += ds * bfhi(v);
                u0 = u1; u1 = u2; u2 = u3;
                c0 = c1v; c1v = c2v; c2v = c3v;
                m0 = m1; m1 = m2; m2 = m3; m3 = MSK(i + 4);
                sF = sN;
            }
        } else {
            int sF = s3;
#pragma unroll 2
            for (int i = 0; i < mx; ++i) {
                int sN = SIDX(i + 4);
                uint4 u3 = ROW(sF);
                u32 v;
                v = u0.x & m0; a0 += bflo(v); a1 += bfhi(v);
                v = u0.y & m0; a2 += bflo(v); a3 += bfhi(v);
                v = u0.z & m0; a4 += bflo(v); a5 += bfhi(v);
                v = u0.w & m0; a6 += bflo(v); a7 += bfhi(v);
                u0 = u1; u1 = u2; u2 = u3;
                m0 = m1; m1 = m2; m2 = m3; m3 = MSK(i + 4);
                sF = sN;
            }
        }
    }
#undef SIDX
#undef ROW
#undef MSK
    uint4 o;
    o.x = pack2(dn * a1, dn * a0);
    o.y = pack2(dn * a3, dn * a2);
    o.z = pack2(dn * a5, dn * a4);
    o.w = pack2(dn * a7, dn * a6);
    *(uint4*)&tl[nn][sl16 * 4] = o;
    __syncthreads();

    // MFMA phase: rows 0..15 of tile @ Bt (128x128), per-wave 2 col-tiles
    int m = lane & 15, kg = lane >> 4;
    floatx4 acc[2];
    acc[0] = (floatx4){0.f, 0.f, 0.f, 0.f};
    acc[1] = (floatx4){0.f, 0.f, 0.f, 0.f};
#pragma unroll
    for (int kk = 0; kk < 4; ++kk) {
        int k0 = kk * 32 + kg * 8;  // bf16 k index
        short8 a = *(const short8*)&tl[m][kk * 16 + kg * 4];
#pragma unroll
        for (int j = 0; j < 2; ++j) {
            int nt = wv * 2 + j;
            short8 b = *(const short8*)(Bt + (size_t)(nt * 16 + m) * DIM + k0);
            acc[j] = __builtin_amdgcn_mfma_f32_16x16x32_bf16(a, b, acc[j], 0, 0, 0);
        }
    }
    float4 d4 = make_float4(1.f, 1.f, 1.f, 1.f);
    if (mode == 0) {
        int4 cr = *(const int4*)(cur + node0 + kg * 4);
        d4.x = rsqrtf((float)(cr.x + 1));
        d4.y = rsqrtf((float)(cr.y + 1));
        d4.z = rsqrtf((float)(cr.z + 1));
        d4.w = rsqrtf((float)(cr.w + 1));
    }
#pragma unroll
    for (int j = 0; j < 2; ++j) {
        int col = (wv * 2 + j) * 16 + m;
        float bv = bias[col];
#pragma unroll
        for (int r = 0; r < 4; ++r) {
            int row = node0 + kg * 4 + r;  // C/D: col=lane&15, row=(lane>>4)*4+reg
            float v = acc[j][r] + bv;
            v = v > 0.f ? v : 0.f;
            if (mode == 0)
                ((u16*)out)[(size_t)row * DIM + col] = f2bf(v * (&d4.x)[r]);
            else
                ((float*)out)[(size_t)row * DIM + col] = v;
        }
    }
}

extern "C" void kernel_launch(void* const* d_in, const int* in_sizes, int n_in,
                              void* d_out, int out_size, void* d_ws, size_t ws_size,
                              hipStream_t stream) {
    (void)in_sizes; (void)n_in; (void)out_size; (void)ws_size;
    const float* x  = (const float*)d_in[0];
    const int*   ei = (const int*)d_in[1];
    const float* W1 = (const float*)d_in[2];
    const float* b1 = (const float*)d_in[3];
    const float* W2 = (const float*)d_in[4];
    const float* b2 = (const float*)d_in[5];
    char* ws = (char*)d_ws;

    u16* W1t = (u16*)(ws + OFF_W1T);
    u16* W2t = (u16*)(ws + OFF_W2T);
    u32* y   = (u32*)(ws + OFF_Y);
    u32* z1  = (u32*)(ws + OFF_Z1);

    k_z<<<128, 256, 0, stream>>>(ei, W1, W2, ws);
    k_fillpack<<<NN * 32 / 256, 256, 0, stream>>>(ei, x, ws);
    // layer 1: z1 = dinv * relu(Ahat(x) @ W1 + b1)   (bf16, pre-scaled)
    k_layer<<<NN / 16, 256, 0, stream>>>(y, ws, W1t, b1, z1, 0);
    // layer 2: out = relu(Ahat(z1) @ W2 + b2)        (f32)
    k_layer<<<NN / 16, 256, 0, stream>>>(z1, ws, W2t, b2, d_out, 1);
}